// Round 1
// baseline (667.040 us; speedup 1.0000x reference)
//
#include <hip/hip_runtime.h>

// Painting: sequentially alpha-composite N RGBA layers onto a white canvas.
//   canvas = canvas*(1 - a) + a*poly,  a = poly[:,3]*0.8  (broadcast over RGBA)
// polys layout: (N, 1, 4, H, W) fp32 row-major. Output: (1, 4, H, W) fp32.
// Per-pixel independent scan -> one thread owns 4 contiguous pixels (float4),
// canvas lives in 16 VGPRs, loop over N. Pure HBM stream: 512 MiB read.

#define PH 512
#define PW 512
#define PHW (PH * PW)
#define PHW4 (PHW / 4)          // float4 groups per plane
#define OPACITY 0.8f

__device__ __forceinline__ void composite(float4& c, const float4& p, const float4& a) {
    // c = c*(1-a) + a*p  ==  c + a*(p - c)
    c.x = fmaf(a.x, p.x - c.x, c.x);
    c.y = fmaf(a.y, p.y - c.y, c.y);
    c.z = fmaf(a.z, p.z - c.z, c.z);
    c.w = fmaf(a.w, p.w - c.w, c.w);
}

__global__ __launch_bounds__(256) void paint_kernel(const float4* __restrict__ polys,
                                                    float4* __restrict__ out,
                                                    int n_polys) {
    const int idx = blockIdx.x * blockDim.x + threadIdx.x;  // 0 .. PHW4-1
    if (idx >= PHW4) return;

    const float4 one = make_float4(1.f, 1.f, 1.f, 1.f);
    float4 c0 = one, c1 = one, c2 = one, c3 = one;   // RGBA canvas, 4 pixels each

    const float4* p = polys + idx;
    #pragma unroll 4
    for (int n = 0; n < n_polys; ++n) {
        // 4 coalesced 16B loads: R,G,B,A planes of layer n
        const float4 p0 = p[0 * PHW4];
        const float4 p1 = p[1 * PHW4];
        const float4 p2 = p[2 * PHW4];
        const float4 p3 = p[3 * PHW4];
        p += 4 * PHW4;

        const float4 a = make_float4(p3.x * OPACITY, p3.y * OPACITY,
                                     p3.z * OPACITY, p3.w * OPACITY);
        composite(c0, p0, a);
        composite(c1, p1, a);
        composite(c2, p2, a);
        composite(c3, p3, a);
    }

    out[0 * PHW4 + idx] = c0;
    out[1 * PHW4 + idx] = c1;
    out[2 * PHW4 + idx] = c2;
    out[3 * PHW4 + idx] = c3;
}

extern "C" void kernel_launch(void* const* d_in, const int* in_sizes, int n_in,
                              void* d_out, int out_size, void* d_ws, size_t ws_size,
                              hipStream_t stream) {
    const float* polys = (const float*)d_in[0];
    float* out = (float*)d_out;

    // N derived from flat input size; H=W=512 fixed by the reference setup.
    const int n_polys = in_sizes[0] / (4 * PHW);

    const int threads = 256;
    const int blocks = (PHW4 + threads - 1) / threads;  // 256 blocks
    paint_kernel<<<blocks, threads, 0, stream>>>((const float4*)polys,
                                                 (float4*)out, n_polys);
}